// Round 10
// baseline (152.709 us; speedup 1.0000x reference)
//
#include <hip/hip_runtime.h>
#include <math.h>

typedef __bf16 b16x8 __attribute__((ext_vector_type(8)));
typedef float  f32x4 __attribute__((ext_vector_type(4)));

#define B_    8
#define CIN_  64
#define COUT_ 64
#define Hs    96
#define Ws    96
#define PLANE (Hs*Ws)        // 9216
#define IMG   (CIN_*PLANE)   // 589824
#define NP    (B_*PLANE)     // 73728
#define NBLK  576            // 128 px per block
#define BPI   72             // blocks per image -> 1 image per XCD

__device__ __forceinline__ int swz(int bid) { return (bid & 7) * BPI + (bid >> 3); }

// Merged aux: x [b][c][y][x] fp32 -> xT [b][y][x][c] bf16, plus weight pre-swizzle
// into per-lane MFMA A-fragment order (same mapping as R5-R9). 288 blocks x 256.
__global__ void aux(const float* __restrict__ x, const float* __restrict__ weight,
                    const float* __restrict__ w_off,
                    __bf16* __restrict__ xT, __bf16* __restrict__ wAB, __bf16* __restrict__ wAO) {
    int i = blockIdx.x * 256 + threadIdx.x;
    {   // transpose to channel-last bf16
        int b = i / PLANE, r = i - b * PLANE;
        const float* src = x + b * IMG + r;
        __bf16 buf[64];
#pragma unroll
        for (int c = 0; c < 64; ++c) buf[c] = (__bf16)src[c * PLANE];
        b16x8* dst = (b16x8*)(xT + (size_t)i * 64);
#pragma unroll
        for (int j = 0; j < 8; ++j) dst[j] = ((const b16x8*)buf)[j];
    }
    if (i < 36864) {
        int e = i & 7, lane = (i >> 3) & 63, mt = (i >> 9) & 3, ks = (i >> 11) & 1, k = i >> 12;
        int o = mt * 16 + (lane & 15);
        int c = ks * 32 + ((lane >> 4) << 3) + e;
        wAB[i] = (__bf16)weight[o * 576 + c * 9 + k];
    }
    if (i < 18432) {
        int e = i & 7, lane = (i >> 3) & 63, mt = (i >> 9) & 1, ks = (i >> 10) & 1, t = i >> 11;
        int ch = mt * 16 + (lane & 15);
        int c  = ks * 32 + ((lane >> 4) << 3) + e;
        wAO[i] = (ch < 27) ? (__bf16)w_off[ch * 576 + c * 9 + t] : (__bf16)(0.f);
    }
}

struct TapCoef { int o00, o01, o10, o11; float v00, v01, v10, v11; };

// N=32 per wave: two 16-px strips share the same A-fragments (halves weight
// traffic) and give 16 independent gather octets + 2 independent combine->MFMA
// chains per tap. Barrier-free, wave-private om in LDS. 576 blocks, 1 img/XCD.
__global__ __launch_bounds__(256, 2)
void deform_mfma(const __bf16* __restrict__ xT,
                 const __bf16* __restrict__ wAO,
                 const float* __restrict__ b_off,
                 const __bf16* __restrict__ wAB,
                 const float* __restrict__ bias,
                 float* __restrict__ out) {
    __shared__ float omL[4][2 * 27 * 16];   // 13824 B, wave-private, per strip

    int tid  = threadIdx.x;
    int lane = tid & 63;
    int g    = __builtin_amdgcn_readfirstlane(tid >> 6);
    int n    = lane & 15;
    int q    = lane >> 4;    // octet: channels q*8..q*8+7 (ks0) / +32 (ks1)

    int sb   = swz(blockIdx.x);
    int b    = sb / BPI;
    int rblk = sb * 128 - b * PLANE;
    int r0   = rblk + g * 32 + n;        // strip 0 pixel
    int r1   = r0 + 16;                  // strip 1 pixel
    int h0 = r0 / Ws, w0 = r0 - h0 * Ws;
    int h1 = r1 / Ws, w1 = r1 - h1 * Ws;
    const __bf16* xTB = xT + (size_t)b * PLANE * 64 + q * 8;

    float* omW0 = &omL[g][0];
    float* omW1 = &omL[g][432];
    const b16x8* wAOv = (const b16x8*)wAO;
    const b16x8* wABv = (const b16x8*)wAB;

#define LD(off) (*(const b16x8*)(xTB + (off)))

    // ---------------- Phase A: offset conv via MFMA, both strips ----------------
    f32x4 A00 = {0.f,0.f,0.f,0.f}, A01 = {0.f,0.f,0.f,0.f};
    f32x4 A10 = {0.f,0.f,0.f,0.f}, A11 = {0.f,0.f,0.f,0.f};

    auto posA = [&](int t, int hh, int ww, bool* mk) -> int {
        int ky = t / 3, kx = t - ky * 3;
        int yy = hh - 1 + ky, xx = ww - 1 + kx;
        *mk = (yy >= 0 && yy < Hs && xx >= 0 && xx < Ws);
        return (min(max(yy, 0), Hs - 1) * Ws + min(max(xx, 0), Ws - 1)) * 64;
    };

    bool mk0, mk1;
    int oA0 = posA(0, h0, w0, &mk0), oA1 = posA(0, h1, w1, &mk1);
    b16x8 eA0 = LD(oA0), qA0 = LD(oA0 + 32);
    b16x8 eA1 = LD(oA1), qA1 = LD(oA1 + 32);
    const b16x8 ZER = {};

#pragma unroll 1
    for (int t = 0; t < 9; ++t) {
        b16x8 af0 = wAOv[((t * 2 + 0) * 2 + 0) * 64 + lane];
        b16x8 af1 = wAOv[((t * 2 + 0) * 2 + 1) * 64 + lane];
        b16x8 af2 = wAOv[((t * 2 + 1) * 2 + 0) * 64 + lane];
        b16x8 af3 = wAOv[((t * 2 + 1) * 2 + 1) * 64 + lane];

        b16x8 b00 = mk0 ? eA0 : ZER, b10 = mk0 ? qA0 : ZER;
        b16x8 b01 = mk1 ? eA1 : ZER, b11 = mk1 ? qA1 : ZER;

        if (t < 8) {   // prefetch next tap, both strips (covered by 8 MFMAs)
            oA0 = posA(t + 1, h0, w0, &mk0);
            oA1 = posA(t + 1, h1, w1, &mk1);
            eA0 = LD(oA0); qA0 = LD(oA0 + 32);
            eA1 = LD(oA1); qA1 = LD(oA1 + 32);
        }

        A00 = __builtin_amdgcn_mfma_f32_16x16x32_bf16(af0, b00, A00, 0, 0, 0);
        A01 = __builtin_amdgcn_mfma_f32_16x16x32_bf16(af1, b00, A01, 0, 0, 0);
        A00 = __builtin_amdgcn_mfma_f32_16x16x32_bf16(af2, b10, A00, 0, 0, 0);
        A01 = __builtin_amdgcn_mfma_f32_16x16x32_bf16(af3, b10, A01, 0, 0, 0);
        A10 = __builtin_amdgcn_mfma_f32_16x16x32_bf16(af0, b01, A10, 0, 0, 0);
        A11 = __builtin_amdgcn_mfma_f32_16x16x32_bf16(af1, b01, A11, 0, 0, 0);
        A10 = __builtin_amdgcn_mfma_f32_16x16x32_bf16(af2, b11, A10, 0, 0, 0);
        A11 = __builtin_amdgcn_mfma_f32_16x16x32_bf16(af3, b11, A11, 0, 0, 0);
    }
#pragma unroll
    for (int rg = 0; rg < 4; ++rg) {
        int ch = q * 4 + rg;
        omW0[ch * 16 + n] = A00[rg] + b_off[ch];
        omW1[ch * 16 + n] = A10[rg] + b_off[ch];
    }
#pragma unroll
    for (int rg = 0; rg < 4; ++rg) {
        int ch = 16 + q * 4 + rg;
        if (ch < 27) {
            omW0[ch * 16 + n] = A01[rg] + b_off[ch];
            omW1[ch * 16 + n] = A11[rg] + b_off[ch];
        }
    }
    // wave-private LDS: in-order within the wave, no barrier needed.

    // ---------------- Phase B: sampling + main conv, both strips ----------------
    f32x4 c00 = {0.f,0.f,0.f,0.f}, c01 = {0.f,0.f,0.f,0.f}, c02 = {0.f,0.f,0.f,0.f}, c03 = {0.f,0.f,0.f,0.f};
    f32x4 c10 = {0.f,0.f,0.f,0.f}, c11 = {0.f,0.f,0.f,0.f}, c12 = {0.f,0.f,0.f,0.f}, c13 = {0.f,0.f,0.f,0.f};

    auto calcB = [&](float dy, float dx, float mo, int kk, int hh, int ww) -> TapCoef {
        TapCoef tc;
        float m  = 1.f / (1.f + __expf(-mo));
        int ky = kk / 3, kx = kk - ky * 3;
        float ys = (float)(hh - 1 + ky) + dy;
        float xs = (float)(ww - 1 + kx) + dx;
        float y0f = floorf(ys), x0f = floorf(xs);
        float ly = ys - y0f, lx = xs - x0f;
        float hy = 1.f - ly, hx = 1.f - lx;
        int y0 = (int)y0f, x0 = (int)x0f, y1 = y0 + 1, x1 = x0 + 1;
        bool vy0 = (y0 >= 0) && (y0 < Hs), vy1 = (y1 >= 0) && (y1 < Hs);
        bool vx0 = (x0 >= 0) && (x0 < Ws), vx1 = (x1 >= 0) && (x1 < Ws);
        tc.v00 = (vy0 && vx0) ? m * hy * hx : 0.f;
        tc.v01 = (vy0 && vx1) ? m * hy * lx : 0.f;
        tc.v10 = (vy1 && vx0) ? m * ly * hx : 0.f;
        tc.v11 = (vy1 && vx1) ? m * ly * lx : 0.f;
        int y0c = min(max(y0, 0), Hs - 1), y1c = min(max(y1, 0), Hs - 1);
        int x0c = min(max(x0, 0), Ws - 1), x1c = min(max(x1, 0), Ws - 1);
        tc.o00 = (y0c * Ws + x0c) * 64; tc.o01 = (y0c * Ws + x1c) * 64;
        tc.o10 = (y1c * Ws + x0c) * 64; tc.o11 = (y1c * Ws + x1c) * 64;
        return tc;
    };

    TapCoef t0, t1;
    {
        float dyA = omW0[0 + n], dxA = omW0[16 + n], moA = omW0[18 * 16 + n];
        float dyB = omW1[0 + n], dxB = omW1[16 + n], moB = omW1[18 * 16 + n];
        t0 = calcB(dyA, dxA, moA, 0, h0, w0);
        t1 = calcB(dyB, dxB, moB, 0, h1, w1);
    }
    b16x8 e00_0 = LD(t0.o00), e01_0 = LD(t0.o01), e10_0 = LD(t0.o10), e11_0 = LD(t0.o11);
    b16x8 e00_1 = LD(t1.o00), e01_1 = LD(t1.o01), e10_1 = LD(t1.o10), e11_1 = LD(t1.o11);

#pragma unroll 1
    for (int k = 0; k < 9; ++k) {
        b16x8 a0 = wABv[(k * 8 + 0) * 64 + lane];
        b16x8 a1 = wABv[(k * 8 + 1) * 64 + lane];
        b16x8 a2 = wABv[(k * 8 + 2) * 64 + lane];
        b16x8 a3 = wABv[(k * 8 + 3) * 64 + lane];
        // ks1 octets (channels +32), both strips
        b16x8 q00_0 = LD(t0.o00 + 32), q01_0 = LD(t0.o01 + 32), q10_0 = LD(t0.o10 + 32), q11_0 = LD(t0.o11 + 32);
        b16x8 q00_1 = LD(t1.o00 + 32), q01_1 = LD(t1.o01 + 32), q10_1 = LD(t1.o10 + 32), q11_1 = LD(t1.o11 + 32);

        int kn = (k < 8) ? (k + 1) : 8;
        float dyA = omW0[(2 * kn) * 16 + n], dxA = omW0[(2 * kn + 1) * 16 + n], moA = omW0[(18 + kn) * 16 + n];
        float dyB = omW1[(2 * kn) * 16 + n], dxB = omW1[(2 * kn + 1) * 16 + n], moB = omW1[(18 + kn) * 16 + n];

        b16x8 fe0;
#pragma unroll
        for (int j = 0; j < 8; ++j)
            fe0[j] = (__bf16)((float)e00_0[j] * t0.v00 + (float)e01_0[j] * t0.v01 +
                              (float)e10_0[j] * t0.v10 + (float)e11_0[j] * t0.v11);
        c00 = __builtin_amdgcn_mfma_f32_16x16x32_bf16(a0, fe0, c00, 0, 0, 0);
        c01 = __builtin_amdgcn_mfma_f32_16x16x32_bf16(a1, fe0, c01, 0, 0, 0);
        c02 = __builtin_amdgcn_mfma_f32_16x16x32_bf16(a2, fe0, c02, 0, 0, 0);
        c03 = __builtin_amdgcn_mfma_f32_16x16x32_bf16(a3, fe0, c03, 0, 0, 0);

        b16x8 fe1;
#pragma unroll
        for (int j = 0; j < 8; ++j)
            fe1[j] = (__bf16)((float)e00_1[j] * t1.v00 + (float)e01_1[j] * t1.v01 +
                              (float)e10_1[j] * t1.v10 + (float)e11_1[j] * t1.v11);
        c10 = __builtin_amdgcn_mfma_f32_16x16x32_bf16(a0, fe1, c10, 0, 0, 0);
        c11 = __builtin_amdgcn_mfma_f32_16x16x32_bf16(a1, fe1, c11, 0, 0, 0);
        c12 = __builtin_amdgcn_mfma_f32_16x16x32_bf16(a2, fe1, c12, 0, 0, 0);
        c13 = __builtin_amdgcn_mfma_f32_16x16x32_bf16(a3, fe1, c13, 0, 0, 0);

        b16x8 a4 = wABv[(k * 8 + 4) * 64 + lane];
        b16x8 a5 = wABv[(k * 8 + 5) * 64 + lane];
        b16x8 a6 = wABv[(k * 8 + 6) * 64 + lane];
        b16x8 a7 = wABv[(k * 8 + 7) * 64 + lane];

        TapCoef n0 = t0, n1 = t1;
        if (k < 8) {   // CALC(k+1) + issue next-tap ks0 octets (covered below)
            n0 = calcB(dyA, dxA, moA, k + 1, h0, w0);
            n1 = calcB(dyB, dxB, moB, k + 1, h1, w1);
            e00_0 = LD(n0.o00); e01_0 = LD(n0.o01); e10_0 = LD(n0.o10); e11_0 = LD(n0.o11);
            e00_1 = LD(n1.o00); e01_1 = LD(n1.o01); e10_1 = LD(n1.o10); e11_1 = LD(n1.o11);
        }

        b16x8 fo0;
#pragma unroll
        for (int j = 0; j < 8; ++j)
            fo0[j] = (__bf16)((float)q00_0[j] * t0.v00 + (float)q01_0[j] * t0.v01 +
                              (float)q10_0[j] * t0.v10 + (float)q11_0[j] * t0.v11);
        c00 = __builtin_amdgcn_mfma_f32_16x16x32_bf16(a4, fo0, c00, 0, 0, 0);
        c01 = __builtin_amdgcn_mfma_f32_16x16x32_bf16(a5, fo0, c01, 0, 0, 0);
        c02 = __builtin_amdgcn_mfma_f32_16x16x32_bf16(a6, fo0, c02, 0, 0, 0);
        c03 = __builtin_amdgcn_mfma_f32_16x16x32_bf16(a7, fo0, c03, 0, 0, 0);

        b16x8 fo1;
#pragma unroll
        for (int j = 0; j < 8; ++j)
            fo1[j] = (__bf16)((float)q00_1[j] * t1.v00 + (float)q01_1[j] * t1.v01 +
                              (float)q10_1[j] * t1.v10 + (float)q11_1[j] * t1.v11);
        c10 = __builtin_amdgcn_mfma_f32_16x16x32_bf16(a4, fo1, c10, 0, 0, 0);
        c11 = __builtin_amdgcn_mfma_f32_16x16x32_bf16(a5, fo1, c11, 0, 0, 0);
        c12 = __builtin_amdgcn_mfma_f32_16x16x32_bf16(a6, fo1, c12, 0, 0, 0);
        c13 = __builtin_amdgcn_mfma_f32_16x16x32_bf16(a7, fo1, c13, 0, 0, 0);

        t0 = n0; t1 = n1;
    }
#undef LD

    // epilogue: C layout row=(q*4+rg) within m-tile, col=n
    f32x4 bs0 = *(const f32x4*)&bias[q * 4];
    f32x4 bs1 = *(const f32x4*)&bias[16 + q * 4];
    f32x4 bs2 = *(const f32x4*)&bias[32 + q * 4];
    f32x4 bs3 = *(const f32x4*)&bias[48 + q * 4];
    int ob0 = b * (COUT_ * PLANE) + r0;
    int ob1 = b * (COUT_ * PLANE) + r1;
#pragma unroll
    for (int rg = 0; rg < 4; ++rg) {
        int o = q * 4 + rg;
        out[ob0 + o * PLANE] = c00[rg] + bs0[rg];
        out[ob1 + o * PLANE] = c10[rg] + bs0[rg];
    }
#pragma unroll
    for (int rg = 0; rg < 4; ++rg) {
        int o = 16 + q * 4 + rg;
        out[ob0 + o * PLANE] = c01[rg] + bs1[rg];
        out[ob1 + o * PLANE] = c11[rg] + bs1[rg];
    }
#pragma unroll
    for (int rg = 0; rg < 4; ++rg) {
        int o = 32 + q * 4 + rg;
        out[ob0 + o * PLANE] = c02[rg] + bs2[rg];
        out[ob1 + o * PLANE] = c12[rg] + bs2[rg];
    }
#pragma unroll
    for (int rg = 0; rg < 4; ++rg) {
        int o = 48 + q * 4 + rg;
        out[ob0 + o * PLANE] = c03[rg] + bs3[rg];
        out[ob1 + o * PLANE] = c13[rg] + bs3[rg];
    }
}

extern "C" void kernel_launch(void* const* d_in, const int* in_sizes, int n_in,
                              void* d_out, int out_size, void* d_ws, size_t ws_size,
                              hipStream_t stream) {
    const float* x      = (const float*)d_in[0];
    const float* w_off  = (const float*)d_in[1];
    const float* b_off  = (const float*)d_in[2];
    const float* weight = (const float*)d_in[3];
    const float* bias   = (const float*)d_in[4];
    float* out = (float*)d_out;

    char* ws = (char*)d_ws;
    __bf16* wAB = (__bf16*)ws;               //  73728 B
    __bf16* wAO = (__bf16*)(ws + 73728);     //  36864 B
    __bf16* xT  = (__bf16*)(ws + 131072);    // 9437184 B (bf16 channel-last)

    aux<<<NP / 256, 256, 0, stream>>>(x, weight, w_off, xT, wAB, wAO);
    deform_mfma<<<NBLK, 256, 0, stream>>>(xT, wAO, b_off, wAB, bias, out);
}